// Round 11
// baseline (584.254 us; speedup 1.0000x reference)
//
#include <hip/hip_runtime.h>

#define N_NODES 50000
#define E_EDGES 800000
#define F_IN 512
#define HID 128
#define N_LAYERS 4
#define C_OUT 40
#define SCAN_BLOCKS 196   // ceil(50000/256)

typedef __attribute__((ext_vector_type(8))) short bf16x8;
typedef __attribute__((ext_vector_type(4))) float f32x4;

#define MFMA16(a, b, c) __builtin_amdgcn_mfma_f32_16x16x32_bf16(a, b, c, 0, 0, 0)

// split fp32 into bf16 hi (RNE) + bf16 lo (residual); a ~= hi + lo with ~2^-17 rel error
__device__ __forceinline__ void split2(float a, unsigned short& hi, unsigned short& lo) {
    unsigned u = __float_as_uint(a);
    unsigned r = u + 0x7FFFu + ((u >> 16) & 1u);
    hi = (unsigned short)(r >> 16);
    float hf = __uint_as_float(((unsigned)hi) << 16);
    lo = (unsigned short)(__float_as_uint(a - hf) >> 16);
}

// async global->LDS 16B DMA
__device__ __forceinline__ void async16(void* lds, const void* g) {
    __builtin_amdgcn_global_load_lds(
        (const __attribute__((address_space(1))) unsigned*)g,
        (__attribute__((address_space(3))) unsigned*)lds, 16, 0, 0);
}

// ---------------- degree / norm ----------------
__global__ void indeg_count(const int* __restrict__ ei, int* __restrict__ indeg) {
    int e = blockIdx.x * 256 + threadIdx.x;
    if (e < E_EDGES) {
        unsigned d = (unsigned)ei[E_EDGES + e];
        if (d < N_NODES) atomicAdd(&indeg[d], 1);
    }
}

// ---------------- 3-phase parallel exclusive scan (+ dinv fused in p1) ----------------
__global__ void scan_p1(const int* __restrict__ indeg, int* __restrict__ bsum,
                        float* __restrict__ dinv) {
    __shared__ int red[4];
    int i = blockIdx.x * 256 + threadIdx.x;
    int v = (i < N_NODES) ? indeg[i] : 0;
    if (i < N_NODES) dinv[i] = rsqrtf(1.0f + (float)v);   // +1 self-loop
    int s = v;
    #pragma unroll
    for (int off = 32; off > 0; off >>= 1) s += __shfl_down(s, off, 64);
    if ((threadIdx.x & 63) == 0) red[threadIdx.x >> 6] = s;
    __syncthreads();
    if (threadIdx.x == 0) bsum[blockIdx.x] = red[0] + red[1] + red[2] + red[3];
}

__launch_bounds__(256)
__global__ void scan_p2(const int* __restrict__ bsum, int* __restrict__ boff,
                        int* __restrict__ rowptr) {
    __shared__ int s[256];
    int t = threadIdx.x;
    int v = (t < SCAN_BLOCKS) ? bsum[t] : 0;
    s[t] = v;
    __syncthreads();
    #pragma unroll
    for (int off = 1; off < 256; off <<= 1) {
        int a = s[t];
        int b = (t >= off) ? s[t - off] : 0;
        __syncthreads();
        s[t] = a + b;
        __syncthreads();
    }
    if (t < SCAN_BLOCKS) boff[t] = (t == 0) ? 0 : s[t - 1];
    if (t == 255) rowptr[N_NODES] = s[SCAN_BLOCKS - 1];
}

__launch_bounds__(256)
__global__ void scan_p3(const int* __restrict__ indeg, const int* __restrict__ boff,
                        int* __restrict__ rowptr, int* __restrict__ cursor) {
    __shared__ int s[256];
    int t = threadIdx.x;
    int i = blockIdx.x * 256 + t;
    int v = (i < N_NODES) ? indeg[i] : 0;
    s[t] = v;
    __syncthreads();
    #pragma unroll
    for (int off = 1; off < 256; off <<= 1) {
        int a = s[t];
        int b = (t >= off) ? s[t - off] : 0;
        __syncthreads();
        s[t] = a + b;
        __syncthreads();
    }
    if (i < N_NODES) {
        int excl = boff[blockIdx.x] + s[t] - v;
        rowptr[i] = excl;
        cursor[i] = excl;
    }
}

// ---------------- CSR fill: (src, dinv[src]) packed ----------------
__global__ void csr_fill(const int* __restrict__ ei, const float* __restrict__ dinv,
                         int* __restrict__ cursor, int2* __restrict__ csr) {
    int e = blockIdx.x * 256 + threadIdx.x;
    if (e < E_EDGES) {
        unsigned s = (unsigned)ei[e];
        unsigned d = (unsigned)ei[E_EDGES + e];
        if (s < N_NODES && d < N_NODES) {
            int pos = atomicAdd(&cursor[d], 1);
            csr[pos] = make_int2((int)s, __float_as_int(dinv[s]));
        }
    }
}

// ---------------- merged weight prep: fp32 W[K][N] -> hi/lo bf16 [N][K] ----------------
__global__ void wprep(const float* __restrict__ Wi, const float* __restrict__ Wl,
                      unsigned short* __restrict__ Wth, unsigned short* __restrict__ Wtl,
                      unsigned short* __restrict__ Wlth, unsigned short* __restrict__ Wltl) {
    int idx = blockIdx.x * 256 + threadIdx.x;
    unsigned short hi, lo;
    if (idx < F_IN * HID) {
        int k = idx >> 7, n = idx & 127;
        split2(Wi[idx], hi, lo);
        Wth[(size_t)n * F_IN + k] = hi;
        Wtl[(size_t)n * F_IN + k] = lo;
    } else if (idx < 2 * F_IN * HID) {
        int j = idx - F_IN * HID;
        int l = j >> 14, rem = j & 16383;
        int k = rem >> 7, n = rem & 127;
        split2(Wl[j], hi, lo);
        Wlth[(size_t)l * HID * HID + n * HID + k] = hi;
        Wltl[(size_t)l * HID * HID + n * HID + k] = lo;
    }
}

// ---------------- input GEMM (MFMA split-bf16): x0 = relu(x @ W_in + b) ----------------
// r6-proven structure: BM=64, BK=64, A staged+split in LDS, B[128][64] DMA, 0 conflicts.
__launch_bounds__(256)
__global__ void gemm_in_mfma(const float* __restrict__ x,
                             const unsigned short* __restrict__ Bth,
                             const unsigned short* __restrict__ Btl,
                             const float* __restrict__ bi,
                             float* __restrict__ x0out) {
    __shared__ __align__(16) unsigned short Ah[64 * 64];
    __shared__ __align__(16) unsigned short Al[64 * 64];
    __shared__ __align__(16) unsigned short Bh[128 * 64];
    __shared__ __align__(16) unsigned short Bl[128 * 64];
    const int t = threadIdx.x;
    const int lane = t & 63;
    const int wv = t >> 6;
    const int wr = wv >> 1, wc = wv & 1;
    const int row0 = blockIdx.x * 64;
    const int fr = lane & 15;
    const int fkg = lane >> 4;

    f32x4 acc[2][4] = {};

    for (int k0 = 0; k0 < F_IN; k0 += 64) {
        #pragma unroll
        for (int i = 0; i < 4; i++) {
            int g = t + i * 256;
            int n = g >> 3, j = g & 7;
            int jp = j ^ (n & 7);
            size_t src = (size_t)n * F_IN + k0 + jp * 8;
            async16(&Bh[g * 8], &Bth[src]);
            async16(&Bl[g * 8], &Btl[src]);
        }
        #pragma unroll
        for (int i = 0; i < 4; i++) {
            int q = t + i * 256;
            int r = q >> 4, c4 = q & 15;
            int grow = row0 + r;
            float4 v = make_float4(0.f, 0.f, 0.f, 0.f);
            if (grow < N_NODES) v = *(const float4*)&x[(size_t)grow * F_IN + k0 + c4 * 4];
            ushort4 uh, ul;
            split2(v.x, uh.x, ul.x); split2(v.y, uh.y, ul.y);
            split2(v.z, uh.z, ul.z); split2(v.w, uh.w, ul.w);
            int idx = (r * 64 + c4 * 4) ^ ((r & 7) << 3);
            *(ushort4*)&Ah[idx] = uh;
            *(ushort4*)&Al[idx] = ul;
        }
        __syncthreads();

        #pragma unroll
        for (int kk = 0; kk < 2; kk++) {
            bf16x8 ah[2], al[2];
            #pragma unroll
            for (int mt = 0; mt < 2; mt++) {
                int arow = wr * 32 + mt * 16 + fr;
                int aidx = (arow * 64 + kk * 32 + fkg * 8) ^ ((arow & 7) << 3);
                ah[mt] = *(bf16x8*)&Ah[aidx];
                al[mt] = *(bf16x8*)&Al[aidx];
            }
            #pragma unroll
            for (int nt = 0; nt < 4; nt++) {
                int n = wc * 64 + nt * 16 + fr;
                int bidx = (n * 64 + kk * 32 + fkg * 8) ^ ((n & 7) << 3);
                bf16x8 bh = *(bf16x8*)&Bh[bidx];
                bf16x8 bl = *(bf16x8*)&Bl[bidx];
                #pragma unroll
                for (int mt = 0; mt < 2; mt++) {
                    acc[mt][nt] = MFMA16(al[mt], bh, acc[mt][nt]);
                    acc[mt][nt] = MFMA16(ah[mt], bl, acc[mt][nt]);
                    acc[mt][nt] = MFMA16(ah[mt], bh, acc[mt][nt]);
                }
            }
        }
        __syncthreads();
    }

    const int dcol = lane & 15;
    const int dr0 = (lane >> 4) * 4;
    #pragma unroll
    for (int nt = 0; nt < 4; nt++) {
        int gcol = wc * 64 + nt * 16 + dcol;
        float b = bi[gcol];
        #pragma unroll
        for (int mt = 0; mt < 2; mt++) {
            #pragma unroll
            for (int j = 0; j < 4; j++) {
                int grow = row0 + wr * 32 + mt * 16 + dr0 + j;
                if (grow < N_NODES) {
                    x0out[(size_t)grow * HID + gcol] = fmaxf(acc[mt][nt][j] + b, 0.f);
                }
            }
        }
    }
}

// ---------------- fused aggregate + layer GEMM ----------------
// Block owns 64 nodes. Phase A: B-half DMA issued, then half-wave-per-node CSR gather +
// residual combine in regs -> split2 -> swizzled A hi/lo LDS (comb never hits global).
// Phase B: r6 GEMM body (two 64-k B halves), SReLU epilogue -> hout.
__launch_bounds__(256)
__global__ void agg_gemm(const int* __restrict__ rowptr, const int2* __restrict__ csr,
                         const float* __restrict__ dinv,
                         const float* __restrict__ h, const float* __restrict__ x0,
                         const unsigned short* __restrict__ Bth,
                         const unsigned short* __restrict__ Btl,
                         const float* __restrict__ sb,
                         float* __restrict__ hout) {
    __shared__ __align__(16) unsigned short Ah[64 * 128];   // 16 KB
    __shared__ __align__(16) unsigned short Al[64 * 128];   // 16 KB
    __shared__ __align__(16) unsigned short Bh[128 * 64];   // 16 KB
    __shared__ __align__(16) unsigned short Bl[128 * 64];   // 16 KB
    const int t = threadIdx.x;
    const int lane = t & 63;
    const int wv = t >> 6;
    const int wr = wv >> 1, wc = wv & 1;
    const int row0 = blockIdx.x * 64;

    auto stageB = [&](int khalf) {
        #pragma unroll
        for (int i = 0; i < 4; i++) {
            int g = t + i * 256;
            int n = g >> 3, j = g & 7;
            int jp = j ^ (n & 7);
            size_t src = (size_t)n * HID + khalf + jp * 8;
            async16(&Bh[g * 8], &Bth[src]);
            async16(&Bl[g * 8], &Btl[src]);
        }
    };

    stageB(0);   // DMA runs while we gather

    // ---- gather phase: half-wave per node, 8 nodes each ----
    {
        const int hw = t >> 5;          // 0..7
        const int gl = t & 31;          // lane in half-wave; owns float4 (16B) of row
        const float4* h4 = (const float4*)h;
        const float4* x4 = (const float4*)x0;

        for (int i = 0; i < 8; i++) {
            int r = hw * 8 + i;                 // LDS row 0..63
            int node = row0 + r;
            float4 o = make_float4(0.f, 0.f, 0.f, 0.f);
            if (node < N_NODES) {
                const float dd = dinv[node];
                const int beg = rowptr[node];
                const int end = rowptr[node + 1];
                float4 a0 = make_float4(0.f, 0.f, 0.f, 0.f);
                float4 a1 = make_float4(0.f, 0.f, 0.f, 0.f);
                float4 a2 = make_float4(0.f, 0.f, 0.f, 0.f);
                float4 a3 = make_float4(0.f, 0.f, 0.f, 0.f);
                int e = beg;
                for (; e + 8 <= end; e += 8) {
                    int2 c0 = csr[e + 0], c1 = csr[e + 1], c2 = csr[e + 2], c3 = csr[e + 3];
                    int2 c4 = csr[e + 4], c5 = csr[e + 5], c6 = csr[e + 6], c7 = csr[e + 7];
                    float4 v0 = h4[(size_t)c0.x * 32 + gl];
                    float4 v1 = h4[(size_t)c1.x * 32 + gl];
                    float4 v2 = h4[(size_t)c2.x * 32 + gl];
                    float4 v3 = h4[(size_t)c3.x * 32 + gl];
                    float4 v4 = h4[(size_t)c4.x * 32 + gl];
                    float4 v5 = h4[(size_t)c5.x * 32 + gl];
                    float4 v6 = h4[(size_t)c6.x * 32 + gl];
                    float4 v7 = h4[(size_t)c7.x * 32 + gl];
                    float w0 = __int_as_float(c0.y), w1 = __int_as_float(c1.y);
                    float w2 = __int_as_float(c2.y), w3 = __int_as_float(c3.y);
                    float w4 = __int_as_float(c4.y), w5 = __int_as_float(c5.y);
                    float w6 = __int_as_float(c6.y), w7 = __int_as_float(c7.y);
                    a0.x = fmaf(w0, v0.x, a0.x); a0.y = fmaf(w0, v0.y, a0.y);
                    a0.z = fmaf(w0, v0.z, a0.z); a0.w = fmaf(w0, v0.w, a0.w);
                    a1.x = fmaf(w1, v1.x, a1.x); a1.y = fmaf(w1, v1.y, a1.y);
                    a1.z = fmaf(w1, v1.z, a1.z); a1.w = fmaf(w1, v1.w, a1.w);
                    a2.x = fmaf(w2, v2.x, a2.x); a2.y = fmaf(w2, v2.y, a2.y);
                    a2.z = fmaf(w2, v2.z, a2.z); a2.w = fmaf(w2, v2.w, a2.w);
                    a3.x = fmaf(w3, v3.x, a3.x); a3.y = fmaf(w3, v3.y, a3.y);
                    a3.z = fmaf(w3, v3.z, a3.z); a3.w = fmaf(w3, v3.w, a3.w);
                    a0.x = fmaf(w4, v4.x, a0.x); a0.y = fmaf(w4, v4.y, a0.y);
                    a0.z = fmaf(w4, v4.z, a0.z); a0.w = fmaf(w4, v4.w, a0.w);
                    a1.x = fmaf(w5, v5.x, a1.x); a1.y = fmaf(w5, v5.y, a1.y);
                    a1.z = fmaf(w5, v5.z, a1.z); a1.w = fmaf(w5, v5.w, a1.w);
                    a2.x = fmaf(w6, v6.x, a2.x); a2.y = fmaf(w6, v6.y, a2.y);
                    a2.z = fmaf(w6, v6.z, a2.z); a2.w = fmaf(w6, v6.w, a2.w);
                    a3.x = fmaf(w7, v7.x, a3.x); a3.y = fmaf(w7, v7.y, a3.y);
                    a3.z = fmaf(w7, v7.z, a3.z); a3.w = fmaf(w7, v7.w, a3.w);
                }
                for (; e < end; e++) {
                    int2 c = csr[e];
                    float w = __int_as_float(c.y);
                    float4 v = h4[(size_t)c.x * 32 + gl];
                    a0.x = fmaf(w, v.x, a0.x); a0.y = fmaf(w, v.y, a0.y);
                    a0.z = fmaf(w, v.z, a0.z); a0.w = fmaf(w, v.w, a0.w);
                }
                float4 sum;
                sum.x = (a0.x + a1.x) + (a2.x + a3.x);
                sum.y = (a0.y + a1.y) + (a2.y + a3.y);
                sum.z = (a0.z + a1.z) + (a2.z + a3.z);
                sum.w = (a0.w + a1.w) + (a2.w + a3.w);
                float4 hv = h4[(size_t)node * 32 + gl];
                float4 xv = x4[(size_t)node * 32 + gl];
                const float a = 0.8f * dd;
                o.x = a * fmaf(dd, hv.x, sum.x) + 0.1f * hv.x + 0.1f * xv.x;
                o.y = a * fmaf(dd, hv.y, sum.y) + 0.1f * hv.y + 0.1f * xv.y;
                o.z = a * fmaf(dd, hv.z, sum.z) + 0.1f * hv.z + 0.1f * xv.z;
                o.w = a * fmaf(dd, hv.w, sum.w) + 0.1f * hv.w + 0.1f * xv.w;
            }
            ushort4 uh, ul;
            split2(o.x, uh.x, ul.x); split2(o.y, uh.y, ul.y);
            split2(o.z, uh.z, ul.z); split2(o.w, uh.w, ul.w);
            int idx = (r * 128 + gl * 4) ^ ((r & 7) << 3);
            *(ushort4*)&Ah[idx] = uh;
            *(ushort4*)&Al[idx] = ul;
        }
    }
    __syncthreads();   // A gathered + B half0 DMA drained

    // ---- GEMM phase (r6 body) ----
    const int fr = lane & 15;
    const int fkg = lane >> 4;
    f32x4 acc[2][4] = {};

    #pragma unroll
    for (int half = 0; half < 2; half++) {
        #pragma unroll
        for (int kk2 = 0; kk2 < 2; kk2++) {
            int kk = half * 2 + kk2;
            bf16x8 ah[2], al[2];
            #pragma unroll
            for (int mt = 0; mt < 2; mt++) {
                int arow = wr * 32 + mt * 16 + fr;
                int aidx = (arow * 128 + kk * 32 + fkg * 8) ^ ((arow & 7) << 3);
                ah[mt] = *(bf16x8*)&Ah[aidx];
                al[mt] = *(bf16x8*)&Al[aidx];
            }
            #pragma unroll
            for (int nt = 0; nt < 4; nt++) {
                int n = wc * 64 + nt * 16 + fr;
                int bidx = (n * 64 + kk2 * 32 + fkg * 8) ^ ((n & 7) << 3);
                bf16x8 bh = *(bf16x8*)&Bh[bidx];
                bf16x8 bl = *(bf16x8*)&Bl[bidx];
                #pragma unroll
                for (int mt = 0; mt < 2; mt++) {
                    acc[mt][nt] = MFMA16(al[mt], bh, acc[mt][nt]);
                    acc[mt][nt] = MFMA16(ah[mt], bl, acc[mt][nt]);
                    acc[mt][nt] = MFMA16(ah[mt], bh, acc[mt][nt]);
                }
            }
        }
        if (half == 0) {
            __syncthreads();
            stageB(64);
            __syncthreads();
        }
    }

    const int dcol = lane & 15;
    const int dr0 = (lane >> 4) * 4;
    #pragma unroll
    for (int nt = 0; nt < 4; nt++) {
        int gcol = wc * 64 + nt * 16 + dcol;
        float s = sb[gcol];
        #pragma unroll
        for (int mt = 0; mt < 2; mt++) {
            #pragma unroll
            for (int j = 0; j < 4; j++) {
                int grow = row0 + wr * 32 + mt * 16 + dr0 + j;
                if (grow < N_NODES) {
                    hout[(size_t)grow * HID + gcol] = fmaxf(acc[mt][nt][j], s);
                }
            }
        }
    }
}

// ---------------- output GEMM: out = h @ W_out + b_out (fp32 vector) ----------------
__launch_bounds__(256)
__global__ void gemm_out(const float* __restrict__ h, const float* __restrict__ Wo,
                         const float* __restrict__ bo, float* __restrict__ out) {
    __shared__ float As[64][129];
    __shared__ float Ws[128][40];
    const int t = threadIdx.x;
    const int row0 = blockIdx.x * 64;

    #pragma unroll
    for (int i = 0; i < 8; i++) {
        int q = t + i * 256;
        int r = q >> 5, c4 = q & 31;
        int grow = row0 + r;
        float4 v = make_float4(0.f, 0.f, 0.f, 0.f);
        if (grow < N_NODES) v = *(const float4*)&h[(size_t)grow * HID + c4 * 4];
        As[r][c4 * 4 + 0] = v.x;
        As[r][c4 * 4 + 1] = v.y;
        As[r][c4 * 4 + 2] = v.z;
        As[r][c4 * 4 + 3] = v.w;
    }
    #pragma unroll
    for (int i = 0; i < 20; i++) {
        int idx = t + i * 256;
        Ws[idx / 40][idx % 40] = Wo[idx];
    }
    __syncthreads();

    const int r = t >> 2;
    const int c0 = t & 3;
    float acc[10] = {};
    #pragma unroll 4
    for (int k = 0; k < HID; k++) {
        float a = As[r][k];
        #pragma unroll
        for (int i = 0; i < 10; i++) {
            acc[i] = fmaf(a, Ws[k][c0 + 4 * i], acc[i]);
        }
    }
    int grow = row0 + r;
    if (grow < N_NODES) {
        #pragma unroll
        for (int i = 0; i < 10; i++) {
            out[(size_t)grow * C_OUT + c0 + 4 * i] = acc[i] + bo[c0 + 4 * i];
        }
    }
}

// ---------------- launch ----------------
extern "C" void kernel_launch(void* const* d_in, const int* in_sizes, int n_in,
                              void* d_out, int out_size, void* d_ws, size_t ws_size,
                              hipStream_t stream) {
    const float* x   = (const float*)d_in[0];
    const int*   ei  = (const int*)d_in[1];
    const float* Wi  = (const float*)d_in[2];
    const float* bi  = (const float*)d_in[3];
    const float* Wls = (const float*)d_in[4];
    const float* sbs = (const float*)d_in[5];
    const float* Wo  = (const float*)d_in[6];
    const float* bo  = (const float*)d_in[7];
    float* out = (float*)d_out;

    float* dinv    = (float*)d_ws;
    int*   indeg   = (int*)(dinv + 50176);
    int*   rowptr  = indeg + 50176;
    int*   cursor  = rowptr + 50304;
    int*   bsum    = cursor + 50176;
    int*   boff    = bsum + 256;
    int2*  csr     = (int2*)(boff + 256);           // 800000 int2
    unsigned short* Wth  = (unsigned short*)(csr + 800000);
    unsigned short* Wtl  = Wth + 65536;
    unsigned short* Wlth = Wtl + 65536;
    unsigned short* Wltl = Wlth + 65536;
    float* x0 = (float*)(Wltl + 65536);             // residual anchor = initial h
    float* hB = x0 + (size_t)N_NODES * HID;
    float* hC = hB + (size_t)N_NODES * HID;

    const int edgeBlocks = (E_EDGES + 255) / 256;
    const int gemmBlocks = (N_NODES + 63) / 64;

    hipMemsetAsync(indeg, 0, N_NODES * sizeof(int), stream);
    indeg_count<<<edgeBlocks, 256, 0, stream>>>(ei, indeg);
    scan_p1<<<SCAN_BLOCKS, 256, 0, stream>>>(indeg, bsum, dinv);
    scan_p2<<<1, 256, 0, stream>>>(bsum, boff, rowptr);
    scan_p3<<<SCAN_BLOCKS, 256, 0, stream>>>(indeg, boff, rowptr, cursor);
    csr_fill<<<edgeBlocks, 256, 0, stream>>>(ei, dinv, cursor, csr);
    wprep<<<(2 * F_IN * HID + 255) / 256, 256, 0, stream>>>(Wi, Wls, Wth, Wtl, Wlth, Wltl);

    gemm_in_mfma<<<gemmBlocks, 256, 0, stream>>>(x, Wth, Wtl, bi, x0);

    float* h = x0;
    for (int l = 0; l < N_LAYERS; l++) {
        float* next = (l & 1) ? hC : hB;
        agg_gemm<<<gemmBlocks, 256, 0, stream>>>(rowptr, csr, dinv, h, x0,
                                                 Wlth + (size_t)l * HID * HID,
                                                 Wltl + (size_t)l * HID * HID,
                                                 sbs + (size_t)l * HID, next);
        h = next;
    }

    gemm_out<<<gemmBlocks, 256, 0, stream>>>(h, Wo, bo, out);
}

// Round 12
// 407.956 us; speedup vs baseline: 1.4321x; 1.4321x over previous
//
#include <hip/hip_runtime.h>
#include <hip/hip_fp16.h>

#define N_NODES 50000
#define E_EDGES 800000
#define F_IN 512
#define HID 128
#define N_LAYERS 4
#define C_OUT 40
#define SCAN_BLOCKS 196   // ceil(50000/256)

typedef __attribute__((ext_vector_type(8))) short bf16x8;
typedef __attribute__((ext_vector_type(4))) float f32x4;

#define MFMA16(a, b, c) __builtin_amdgcn_mfma_f32_16x16x32_bf16(a, b, c, 0, 0, 0)

// split fp32 into bf16 hi (RNE) + bf16 lo (residual); a ~= hi + lo with ~2^-17 rel error
__device__ __forceinline__ void split2(float a, unsigned short& hi, unsigned short& lo) {
    unsigned u = __float_as_uint(a);
    unsigned r = u + 0x7FFFu + ((u >> 16) & 1u);
    hi = (unsigned short)(r >> 16);
    float hf = __uint_as_float(((unsigned)hi) << 16);
    lo = (unsigned short)(__float_as_uint(a - hf) >> 16);
}

// async global->LDS 16B DMA
__device__ __forceinline__ void async16(void* lds, const void* g) {
    __builtin_amdgcn_global_load_lds(
        (const __attribute__((address_space(1))) unsigned*)g,
        (__attribute__((address_space(3))) unsigned*)lds, 16, 0, 0);
}

// ---------------- degree ----------------
__global__ void indeg_count(const int* __restrict__ ei, int* __restrict__ indeg) {
    int e = blockIdx.x * 256 + threadIdx.x;
    if (e < E_EDGES) {
        unsigned d = (unsigned)ei[E_EDGES + e];
        if (d < N_NODES) atomicAdd(&indeg[d], 1);
    }
}

// ---------------- 3-phase parallel exclusive scan (+ dinv fused in p1) ----------------
__global__ void scan_p1(const int* __restrict__ indeg, int* __restrict__ bsum,
                        float* __restrict__ dinv) {
    __shared__ int red[4];
    int i = blockIdx.x * 256 + threadIdx.x;
    int v = (i < N_NODES) ? indeg[i] : 0;
    if (i < N_NODES) dinv[i] = rsqrtf(1.0f + (float)v);   // +1 self-loop
    int s = v;
    #pragma unroll
    for (int off = 32; off > 0; off >>= 1) s += __shfl_down(s, off, 64);
    if ((threadIdx.x & 63) == 0) red[threadIdx.x >> 6] = s;
    __syncthreads();
    if (threadIdx.x == 0) bsum[blockIdx.x] = red[0] + red[1] + red[2] + red[3];
}

__launch_bounds__(256)
__global__ void scan_p2(const int* __restrict__ bsum, int* __restrict__ boff,
                        int* __restrict__ rowptr) {
    __shared__ int s[256];
    int t = threadIdx.x;
    int v = (t < SCAN_BLOCKS) ? bsum[t] : 0;
    s[t] = v;
    __syncthreads();
    #pragma unroll
    for (int off = 1; off < 256; off <<= 1) {
        int a = s[t];
        int b = (t >= off) ? s[t - off] : 0;
        __syncthreads();
        s[t] = a + b;
        __syncthreads();
    }
    if (t < SCAN_BLOCKS) boff[t] = (t == 0) ? 0 : s[t - 1];
    if (t == 255) rowptr[N_NODES] = s[SCAN_BLOCKS - 1];
}

__launch_bounds__(256)
__global__ void scan_p3(const int* __restrict__ indeg, const int* __restrict__ boff,
                        int* __restrict__ rowptr, int* __restrict__ cursor) {
    __shared__ int s[256];
    int t = threadIdx.x;
    int i = blockIdx.x * 256 + t;
    int v = (i < N_NODES) ? indeg[i] : 0;
    s[t] = v;
    __syncthreads();
    #pragma unroll
    for (int off = 1; off < 256; off <<= 1) {
        int a = s[t];
        int b = (t >= off) ? s[t - off] : 0;
        __syncthreads();
        s[t] = a + b;
        __syncthreads();
    }
    if (i < N_NODES) {
        int excl = boff[blockIdx.x] + s[t] - v;
        rowptr[i] = excl;
        cursor[i] = excl;
    }
}

// ---------------- CSR fill: plain src (weights pre-scaled into g16) ----------------
__global__ void csr_fill(const int* __restrict__ ei, int* __restrict__ cursor,
                         int* __restrict__ csr) {
    int e = blockIdx.x * 256 + threadIdx.x;
    if (e < E_EDGES) {
        unsigned s = (unsigned)ei[e];
        unsigned d = (unsigned)ei[E_EDGES + e];
        if (s < N_NODES && d < N_NODES) {
            int pos = atomicAdd(&cursor[d], 1);
            csr[pos] = (int)s;
        }
    }
}

// ---------------- merged weight prep: fp32 W[K][N] -> hi/lo bf16 [N][K] ----------------
__global__ void wprep(const float* __restrict__ Wi, const float* __restrict__ Wl,
                      unsigned short* __restrict__ Wth, unsigned short* __restrict__ Wtl,
                      unsigned short* __restrict__ Wlth, unsigned short* __restrict__ Wltl) {
    int idx = blockIdx.x * 256 + threadIdx.x;
    unsigned short hi, lo;
    if (idx < F_IN * HID) {
        int k = idx >> 7, n = idx & 127;
        split2(Wi[idx], hi, lo);
        Wth[(size_t)n * F_IN + k] = hi;
        Wtl[(size_t)n * F_IN + k] = lo;
    } else if (idx < 2 * F_IN * HID) {
        int j = idx - F_IN * HID;
        int l = j >> 14, rem = j & 16383;
        int k = rem >> 7, n = rem & 127;
        split2(Wl[j], hi, lo);
        Wlth[(size_t)l * HID * HID + n * HID + k] = hi;
        Wltl[(size_t)l * HID * HID + n * HID + k] = lo;
    }
}

// ---------------- input GEMM (MFMA split-bf16): x0 = relu(x@W_in+b), g16 = fp16(dinv*x0) ----------------
// r6-proven structure: BM=64, BK=64, A staged+split in LDS, B[128][64] DMA, 0 conflicts.
__launch_bounds__(256)
__global__ void gemm_in_mfma(const float* __restrict__ x,
                             const unsigned short* __restrict__ Bth,
                             const unsigned short* __restrict__ Btl,
                             const float* __restrict__ bi,
                             const float* __restrict__ dinv,
                             float* __restrict__ x0out,
                             __half* __restrict__ g16) {
    __shared__ __align__(16) unsigned short Ah[64 * 64];
    __shared__ __align__(16) unsigned short Al[64 * 64];
    __shared__ __align__(16) unsigned short Bh[128 * 64];
    __shared__ __align__(16) unsigned short Bl[128 * 64];
    const int t = threadIdx.x;
    const int lane = t & 63;
    const int wv = t >> 6;
    const int wr = wv >> 1, wc = wv & 1;
    const int row0 = blockIdx.x * 64;
    const int fr = lane & 15;
    const int fkg = lane >> 4;

    f32x4 acc[2][4] = {};

    for (int k0 = 0; k0 < F_IN; k0 += 64) {
        #pragma unroll
        for (int i = 0; i < 4; i++) {
            int g = t + i * 256;
            int n = g >> 3, j = g & 7;
            int jp = j ^ (n & 7);
            size_t src = (size_t)n * F_IN + k0 + jp * 8;
            async16(&Bh[g * 8], &Bth[src]);
            async16(&Bl[g * 8], &Btl[src]);
        }
        #pragma unroll
        for (int i = 0; i < 4; i++) {
            int q = t + i * 256;
            int r = q >> 4, c4 = q & 15;
            int grow = row0 + r;
            float4 v = make_float4(0.f, 0.f, 0.f, 0.f);
            if (grow < N_NODES) v = *(const float4*)&x[(size_t)grow * F_IN + k0 + c4 * 4];
            ushort4 uh, ul;
            split2(v.x, uh.x, ul.x); split2(v.y, uh.y, ul.y);
            split2(v.z, uh.z, ul.z); split2(v.w, uh.w, ul.w);
            int idx = (r * 64 + c4 * 4) ^ ((r & 7) << 3);
            *(ushort4*)&Ah[idx] = uh;
            *(ushort4*)&Al[idx] = ul;
        }
        __syncthreads();

        #pragma unroll
        for (int kk = 0; kk < 2; kk++) {
            bf16x8 ah[2], al[2];
            #pragma unroll
            for (int mt = 0; mt < 2; mt++) {
                int arow = wr * 32 + mt * 16 + fr;
                int aidx = (arow * 64 + kk * 32 + fkg * 8) ^ ((arow & 7) << 3);
                ah[mt] = *(bf16x8*)&Ah[aidx];
                al[mt] = *(bf16x8*)&Al[aidx];
            }
            #pragma unroll
            for (int nt = 0; nt < 4; nt++) {
                int n = wc * 64 + nt * 16 + fr;
                int bidx = (n * 64 + kk * 32 + fkg * 8) ^ ((n & 7) << 3);
                bf16x8 bh = *(bf16x8*)&Bh[bidx];
                bf16x8 bl = *(bf16x8*)&Bl[bidx];
                #pragma unroll
                for (int mt = 0; mt < 2; mt++) {
                    acc[mt][nt] = MFMA16(al[mt], bh, acc[mt][nt]);
                    acc[mt][nt] = MFMA16(ah[mt], bl, acc[mt][nt]);
                    acc[mt][nt] = MFMA16(ah[mt], bh, acc[mt][nt]);
                }
            }
        }
        __syncthreads();
    }

    const int dcol = lane & 15;
    const int dr0 = (lane >> 4) * 4;
    // hoist dinv for the 8 rows this lane writes
    float dv[2][4];
    #pragma unroll
    for (int mt = 0; mt < 2; mt++)
        #pragma unroll
        for (int j = 0; j < 4; j++) {
            int grow = row0 + wr * 32 + mt * 16 + dr0 + j;
            dv[mt][j] = (grow < N_NODES) ? dinv[grow] : 0.f;
        }
    #pragma unroll
    for (int nt = 0; nt < 4; nt++) {
        int gcol = wc * 64 + nt * 16 + dcol;
        float b = bi[gcol];
        #pragma unroll
        for (int mt = 0; mt < 2; mt++) {
            #pragma unroll
            for (int j = 0; j < 4; j++) {
                int grow = row0 + wr * 32 + mt * 16 + dr0 + j;
                if (grow < N_NODES) {
                    float v = fmaxf(acc[mt][nt][j] + b, 0.f);
                    x0out[(size_t)grow * HID + gcol] = v;
                    g16[(size_t)grow * HID + gcol] = __float2half(dv[mt][j] * v);
                }
            }
        }
    }
}

// ---------------- aggregate (fp16 pre-scaled gather) + residual combine ----------------
// Half-wave (32 lanes) per dst node; lane owns 4 halves (8B) of the 256B g16 row.
// comb = 0.8*dd*sum(g16[src]) + (0.8*dd^2+0.1)*h[d] + 0.1*x0[d]
__launch_bounds__(256)
__global__ void aggregate(const int* __restrict__ rowptr, const int* __restrict__ csr,
                          const float* __restrict__ dinv,
                          const __half* __restrict__ g16,
                          const float* __restrict__ h, const float* __restrict__ x0,
                          float* __restrict__ comb) {
    const int hw = threadIdx.x >> 5;
    const int gl = threadIdx.x & 31;
    const int node = blockIdx.x * 8 + hw;
    if (node >= N_NODES) return;

    const float dd = dinv[node];
    const int beg = rowptr[node];
    const int end = rowptr[node + 1];

    float a0 = 0.f, a1 = 0.f, a2 = 0.f, a3 = 0.f;

    #define GLOAD(su) (*(const uint2*)(g16 + (size_t)(su) * HID + gl * 4))
    #define GACC(r) { \
        __half2 p0 = *(__half2*)&(r).x, p1 = *(__half2*)&(r).y; \
        float2 f0 = __half22float2(p0), f1 = __half22float2(p1); \
        a0 += f0.x; a1 += f0.y; a2 += f1.x; a3 += f1.y; }

    int e = beg;
    for (; e + 8 <= end; e += 8) {
        int s0 = csr[e + 0], s1 = csr[e + 1], s2 = csr[e + 2], s3 = csr[e + 3];
        int s4 = csr[e + 4], s5 = csr[e + 5], s6 = csr[e + 6], s7 = csr[e + 7];
        uint2 r0 = GLOAD(s0), r1 = GLOAD(s1), r2 = GLOAD(s2), r3 = GLOAD(s3);
        uint2 r4 = GLOAD(s4), r5 = GLOAD(s5), r6 = GLOAD(s6), r7 = GLOAD(s7);
        GACC(r0) GACC(r1) GACC(r2) GACC(r3)
        GACC(r4) GACC(r5) GACC(r6) GACC(r7)
    }
    for (; e + 2 <= end; e += 2) {
        int s0 = csr[e], s1 = csr[e + 1];
        uint2 r0 = GLOAD(s0), r1 = GLOAD(s1);
        GACC(r0) GACC(r1)
    }
    if (e < end) {
        uint2 r0 = GLOAD(csr[e]);
        GACC(r0)
    }
    #undef GLOAD
    #undef GACC

    const float c1 = 0.8f * dd;
    const float c2 = 0.8f * dd * dd + 0.1f;
    float4 hv = ((const float4*)h)[(size_t)node * 32 + gl];
    float4 xv = ((const float4*)x0)[(size_t)node * 32 + gl];
    float4 o;
    o.x = fmaf(c1, a0, fmaf(c2, hv.x, 0.1f * xv.x));
    o.y = fmaf(c1, a1, fmaf(c2, hv.y, 0.1f * xv.y));
    o.z = fmaf(c1, a2, fmaf(c2, hv.z, 0.1f * xv.z));
    o.w = fmaf(c1, a3, fmaf(c2, hv.w, 0.1f * xv.w));
    ((float4*)comb)[(size_t)node * 32 + gl] = o;
}

// ---------------- layer GEMM (MFMA split-bf16, in place): h <- SReLU(comb @ W), g16 ----------------
__launch_bounds__(256)
__global__ void gemm_layer_mfma(const unsigned short* __restrict__ Bth,
                                const unsigned short* __restrict__ Btl,
                                const float* __restrict__ sb,
                                const float* __restrict__ dinv,
                                float* __restrict__ comb,
                                __half* __restrict__ g16, int writeg) {
    __shared__ __align__(16) unsigned short Ah[64 * 128];
    __shared__ __align__(16) unsigned short Al[64 * 128];
    __shared__ __align__(16) unsigned short Bh[128 * 64];
    __shared__ __align__(16) unsigned short Bl[128 * 64];
    const int t = threadIdx.x;
    const int lane = t & 63;
    const int wv = t >> 6;
    const int wr = wv >> 1, wc = wv & 1;
    const int row0 = blockIdx.x * 64;
    const int fr = lane & 15;
    const int fkg = lane >> 4;

    f32x4 acc[2][4] = {};

    auto stageB = [&](int khalf) {
        #pragma unroll
        for (int i = 0; i < 4; i++) {
            int g = t + i * 256;
            int n = g >> 3, j = g & 7;
            int jp = j ^ (n & 7);
            size_t src = (size_t)n * HID + khalf + jp * 8;
            async16(&Bh[g * 8], &Bth[src]);
            async16(&Bl[g * 8], &Btl[src]);
        }
    };

    stageB(0);
    #pragma unroll
    for (int i = 0; i < 8; i++) {
        int q = t + i * 256;
        int r = q >> 5, c4 = q & 31;
        int grow = row0 + r;
        float4 v = make_float4(0.f, 0.f, 0.f, 0.f);
        if (grow < N_NODES) v = *(const float4*)&comb[(size_t)grow * HID + c4 * 4];
        ushort4 uh, ul;
        split2(v.x, uh.x, ul.x); split2(v.y, uh.y, ul.y);
        split2(v.z, uh.z, ul.z); split2(v.w, uh.w, ul.w);
        int idx = (r * 128 + c4 * 4) ^ ((r & 7) << 3);
        *(ushort4*)&Ah[idx] = uh;
        *(ushort4*)&Al[idx] = ul;
    }
    __syncthreads();

    #pragma unroll
    for (int half = 0; half < 2; half++) {
        #pragma unroll
        for (int kk2 = 0; kk2 < 2; kk2++) {
            int kk = half * 2 + kk2;
            bf16x8 ah[2], al[2];
            #pragma unroll
            for (int mt = 0; mt < 2; mt++) {
                int arow = wr * 32 + mt * 16 + fr;
                int aidx = (arow * 128 + kk * 32 + fkg * 8) ^ ((arow & 7) << 3);
                ah[mt] = *(bf16x8*)&Ah[aidx];
                al[mt] = *(bf16x8*)&Al[aidx];
            }
            #pragma unroll
            for (int nt = 0; nt < 4; nt++) {
                int n = wc * 64 + nt * 16 + fr;
                int bidx = (n * 64 + kk2 * 32 + fkg * 8) ^ ((n & 7) << 3);
                bf16x8 bh = *(bf16x8*)&Bh[bidx];
                bf16x8 bl = *(bf16x8*)&Bl[bidx];
                #pragma unroll
                for (int mt = 0; mt < 2; mt++) {
                    acc[mt][nt] = MFMA16(al[mt], bh, acc[mt][nt]);
                    acc[mt][nt] = MFMA16(ah[mt], bl, acc[mt][nt]);
                    acc[mt][nt] = MFMA16(ah[mt], bh, acc[mt][nt]);
                }
            }
        }
        if (half == 0) {
            __syncthreads();
            stageB(64);
            __syncthreads();
        }
    }

    const int dcol = lane & 15;
    const int dr0 = (lane >> 4) * 4;
    float dv[2][4];
    #pragma unroll
    for (int mt = 0; mt < 2; mt++)
        #pragma unroll
        for (int j = 0; j < 4; j++) {
            int grow = row0 + wr * 32 + mt * 16 + dr0 + j;
            dv[mt][j] = (grow < N_NODES) ? dinv[grow] : 0.f;
        }
    #pragma unroll
    for (int nt = 0; nt < 4; nt++) {
        int gcol = wc * 64 + nt * 16 + dcol;
        float s = sb[gcol];
        #pragma unroll
        for (int mt = 0; mt < 2; mt++) {
            #pragma unroll
            for (int j = 0; j < 4; j++) {
                int grow = row0 + wr * 32 + mt * 16 + dr0 + j;
                if (grow < N_NODES) {
                    float v = fmaxf(acc[mt][nt][j], s);
                    comb[(size_t)grow * HID + gcol] = v;
                    if (writeg) g16[(size_t)grow * HID + gcol] = __float2half(dv[mt][j] * v);
                }
            }
        }
    }
}

// ---------------- output GEMM: out = h @ W_out + b_out (fp32 vector) ----------------
__launch_bounds__(256)
__global__ void gemm_out(const float* __restrict__ h, const float* __restrict__ Wo,
                         const float* __restrict__ bo, float* __restrict__ out) {
    __shared__ float As[64][129];
    __shared__ float Ws[128][40];
    const int t = threadIdx.x;
    const int row0 = blockIdx.x * 64;

    #pragma unroll
    for (int i = 0; i < 8; i++) {
        int q = t + i * 256;
        int r = q >> 5, c4 = q & 31;
        int grow = row0 + r;
        float4 v = make_float4(0.f, 0.f, 0.f, 0.f);
        if (grow < N_NODES) v = *(const float4*)&h[(size_t)grow * HID + c4 * 4];
        As[r][c4 * 4 + 0] = v.x;
        As[r][c4 * 4 + 1] = v.y;
        As[r][c4 * 4 + 2] = v.z;
        As[r][c4 * 4 + 3] = v.w;
    }
    #pragma unroll
    for (int i = 0; i < 20; i++) {
        int idx = t + i * 256;
        Ws[idx / 40][idx % 40] = Wo[idx];
    }
    __syncthreads();

    const int r = t >> 2;
    const int c0 = t & 3;
    float acc[10] = {};
    #pragma unroll 4
    for (int k = 0; k < HID; k++) {
        float a = As[r][k];
        #pragma unroll
        for (int i = 0; i < 10; i++) {
            acc[i] = fmaf(a, Ws[k][c0 + 4 * i], acc[i]);
        }
    }
    int grow = row0 + r;
    if (grow < N_NODES) {
        #pragma unroll
        for (int i = 0; i < 10; i++) {
            out[(size_t)grow * C_OUT + c0 + 4 * i] = acc[i] + bo[c0 + 4 * i];
        }
    }
}

// ---------------- launch ----------------
extern "C" void kernel_launch(void* const* d_in, const int* in_sizes, int n_in,
                              void* d_out, int out_size, void* d_ws, size_t ws_size,
                              hipStream_t stream) {
    const float* x   = (const float*)d_in[0];
    const int*   ei  = (const int*)d_in[1];
    const float* Wi  = (const float*)d_in[2];
    const float* bi  = (const float*)d_in[3];
    const float* Wls = (const float*)d_in[4];
    const float* sbs = (const float*)d_in[5];
    const float* Wo  = (const float*)d_in[6];
    const float* bo  = (const float*)d_in[7];
    float* out = (float*)d_out;

    float* dinv    = (float*)d_ws;                  // 50176 f
    int*   indeg   = (int*)(dinv + 50176);          // 50176 i
    int*   rowptr  = indeg + 50176;                 // 50304 i
    int*   cursor  = rowptr + 50304;                // 50176 i
    int*   bsum    = cursor + 50176;                // 256 i
    int*   boff    = bsum + 256;                    // 256 i
    int*   csr     = boff + 256;                    // 800000 i (3.2 MB)
    unsigned short* Wth  = (unsigned short*)(csr + 800000);
    unsigned short* Wtl  = Wth + 65536;
    unsigned short* Wlth = Wtl + 65536;
    unsigned short* Wltl = Wlth + 65536;
    float* x0  = (float*)(Wltl + 65536);            // 6.4M f (residual anchor)
    float* hB  = x0 + (size_t)N_NODES * HID;        // 6.4M f
    float* hC  = hB + (size_t)N_NODES * HID;        // 6.4M f
    __half* g16 = (__half*)(hC + (size_t)N_NODES * HID);  // 6.4M halves (12.8 MB)

    const int edgeBlocks = (E_EDGES + 255) / 256;
    const int gemmBlocks = (N_NODES + 63) / 64;
    const int aggBlocks  = (N_NODES + 7) / 8;

    hipMemsetAsync(indeg, 0, N_NODES * sizeof(int), stream);
    indeg_count<<<edgeBlocks, 256, 0, stream>>>(ei, indeg);
    scan_p1<<<SCAN_BLOCKS, 256, 0, stream>>>(indeg, bsum, dinv);
    scan_p2<<<1, 256, 0, stream>>>(bsum, boff, rowptr);
    scan_p3<<<SCAN_BLOCKS, 256, 0, stream>>>(indeg, boff, rowptr, cursor);
    csr_fill<<<edgeBlocks, 256, 0, stream>>>(ei, cursor, csr);
    wprep<<<(2 * F_IN * HID + 255) / 256, 256, 0, stream>>>(Wi, Wls, Wth, Wtl, Wlth, Wltl);

    gemm_in_mfma<<<gemmBlocks, 256, 0, stream>>>(x, Wth, Wtl, bi, dinv, x0, g16);

    float* h = x0;
    for (int l = 0; l < N_LAYERS; l++) {
        float* next = (l & 1) ? hC : hB;
        aggregate<<<aggBlocks, 256, 0, stream>>>(rowptr, csr, dinv, g16, h, x0, next);
        gemm_layer_mfma<<<gemmBlocks, 256, 0, stream>>>(Wlth + (size_t)l * HID * HID,
                                                        Wltl + (size_t)l * HID * HID,
                                                        sbs + (size_t)l * HID, dinv,
                                                        next, g16,
                                                        (l + 1 < N_LAYERS) ? 1 : 0);
        h = next;
    }

    gemm_out<<<gemmBlocks, 256, 0, stream>>>(h, Wo, bo, out);
}

// Round 13
// 402.606 us; speedup vs baseline: 1.4512x; 1.0133x over previous
//
#include <hip/hip_runtime.h>
#include <hip/hip_fp16.h>

#define N_NODES 50000
#define E_EDGES 800000
#define F_IN 512
#define HID 128
#define N_LAYERS 4
#define C_OUT 40
#define SCAN_BLOCKS 196   // ceil(50000/256)

typedef __attribute__((ext_vector_type(8))) short bf16x8;
typedef __attribute__((ext_vector_type(4))) float f32x4;

#define MFMA16(a, b, c) __builtin_amdgcn_mfma_f32_16x16x32_bf16(a, b, c, 0, 0, 0)

// split fp32 into bf16 hi (RNE) + bf16 lo (residual); a ~= hi + lo with ~2^-17 rel error
__device__ __forceinline__ void split2(float a, unsigned short& hi, unsigned short& lo) {
    unsigned u = __float_as_uint(a);
    unsigned r = u + 0x7FFFu + ((u >> 16) & 1u);
    hi = (unsigned short)(r >> 16);
    float hf = __uint_as_float(((unsigned)hi) << 16);
    lo = (unsigned short)(__float_as_uint(a - hf) >> 16);
}

// async global->LDS 16B DMA
__device__ __forceinline__ void async16(void* lds, const void* g) {
    __builtin_amdgcn_global_load_lds(
        (const __attribute__((address_space(1))) unsigned*)g,
        (__attribute__((address_space(3))) unsigned*)lds, 16, 0, 0);
}

// ---------------- degree ----------------
__global__ void indeg_count(const int* __restrict__ ei, int* __restrict__ indeg) {
    int e = blockIdx.x * 256 + threadIdx.x;
    if (e < E_EDGES) {
        unsigned d = (unsigned)ei[E_EDGES + e];
        if (d < N_NODES) atomicAdd(&indeg[d], 1);
    }
}

// ---------------- 3-phase parallel exclusive scan (+ dinv fused in p1) ----------------
__global__ void scan_p1(const int* __restrict__ indeg, int* __restrict__ bsum,
                        float* __restrict__ dinv) {
    __shared__ int red[4];
    int i = blockIdx.x * 256 + threadIdx.x;
    int v = (i < N_NODES) ? indeg[i] : 0;
    if (i < N_NODES) dinv[i] = rsqrtf(1.0f + (float)v);   // +1 self-loop
    int s = v;
    #pragma unroll
    for (int off = 32; off > 0; off >>= 1) s += __shfl_down(s, off, 64);
    if ((threadIdx.x & 63) == 0) red[threadIdx.x >> 6] = s;
    __syncthreads();
    if (threadIdx.x == 0) bsum[blockIdx.x] = red[0] + red[1] + red[2] + red[3];
}

__launch_bounds__(256)
__global__ void scan_p2(const int* __restrict__ bsum, int* __restrict__ boff,
                        int* __restrict__ rowptr) {
    __shared__ int s[256];
    int t = threadIdx.x;
    int v = (t < SCAN_BLOCKS) ? bsum[t] : 0;
    s[t] = v;
    __syncthreads();
    #pragma unroll
    for (int off = 1; off < 256; off <<= 1) {
        int a = s[t];
        int b = (t >= off) ? s[t - off] : 0;
        __syncthreads();
        s[t] = a + b;
        __syncthreads();
    }
    if (t < SCAN_BLOCKS) boff[t] = (t == 0) ? 0 : s[t - 1];
    if (t == 255) rowptr[N_NODES] = s[SCAN_BLOCKS - 1];
}

__launch_bounds__(256)
__global__ void scan_p3(const int* __restrict__ indeg, const int* __restrict__ boff,
                        int* __restrict__ rowptr, int* __restrict__ cursor) {
    __shared__ int s[256];
    int t = threadIdx.x;
    int i = blockIdx.x * 256 + t;
    int v = (i < N_NODES) ? indeg[i] : 0;
    s[t] = v;
    __syncthreads();
    #pragma unroll
    for (int off = 1; off < 256; off <<= 1) {
        int a = s[t];
        int b = (t >= off) ? s[t - off] : 0;
        __syncthreads();
        s[t] = a + b;
        __syncthreads();
    }
    if (i < N_NODES) {
        int excl = boff[blockIdx.x] + s[t] - v;
        rowptr[i] = excl;
        cursor[i] = excl;
    }
}

// ---------------- CSR fill ----------------
__global__ void csr_fill(const int* __restrict__ ei, int* __restrict__ cursor,
                         int* __restrict__ csr) {
    int e = blockIdx.x * 256 + threadIdx.x;
    if (e < E_EDGES) {
        unsigned s = (unsigned)ei[e];
        unsigned d = (unsigned)ei[E_EDGES + e];
        if (s < N_NODES && d < N_NODES) {
            int pos = atomicAdd(&cursor[d], 1);
            csr[pos] = (int)s;
        }
    }
}

// ---------------- merged weight prep: fp32 W[K][N] -> hi/lo bf16 [N][K] ----------------
__global__ void wprep(const float* __restrict__ Wi, const float* __restrict__ Wl,
                      unsigned short* __restrict__ Wth, unsigned short* __restrict__ Wtl,
                      unsigned short* __restrict__ Wlth, unsigned short* __restrict__ Wltl) {
    int idx = blockIdx.x * 256 + threadIdx.x;
    unsigned short hi, lo;
    if (idx < F_IN * HID) {
        int k = idx >> 7, n = idx & 127;
        split2(Wi[idx], hi, lo);
        Wth[(size_t)n * F_IN + k] = hi;
        Wtl[(size_t)n * F_IN + k] = lo;
    } else if (idx < 2 * F_IN * HID) {
        int j = idx - F_IN * HID;
        int l = j >> 14, rem = j & 16383;
        int k = rem >> 7, n = rem & 127;
        split2(Wl[j], hi, lo);
        Wlth[(size_t)l * HID * HID + n * HID + k] = hi;
        Wltl[(size_t)l * HID * HID + n * HID + k] = lo;
    }
}

// ---------------- input GEMM (MFMA split-bf16): x0 = relu(x@W_in+b), g16 = fp16(dinv*x0) ----------------
// BK=32, 16 steps, LDS 24KB -> 6 blocks/CU (24 waves) for cross-block latency hiding.
// 64B rows: granule swizzle g ^= (row>>1)&3 gives balanced banks on ds_read_b128.
__launch_bounds__(256)
__global__ void gemm_in_mfma(const float* __restrict__ x,
                             const unsigned short* __restrict__ Bth,
                             const unsigned short* __restrict__ Btl,
                             const float* __restrict__ bi,
                             const float* __restrict__ dinv,
                             float* __restrict__ x0out,
                             __half* __restrict__ g16) {
    __shared__ __align__(16) unsigned short Ah[64 * 32];    // 4 KB
    __shared__ __align__(16) unsigned short Al[64 * 32];    // 4 KB
    __shared__ __align__(16) unsigned short Bh[128 * 32];   // 8 KB
    __shared__ __align__(16) unsigned short Bl[128 * 32];   // 8 KB
    const int t = threadIdx.x;
    const int lane = t & 63;
    const int wv = t >> 6;
    const int wr = wv >> 1, wc = wv & 1;
    const int row0 = blockIdx.x * 64;
    const int fr = lane & 15;
    const int fkg = lane >> 4;          // 16B granule 0..3

    f32x4 acc[2][4] = {};

    for (int step = 0; step < 16; step++) {
        const int k0 = step * 32;
        // B DMA: [128n][32k] hi/lo; source granule carries the swizzle
        #pragma unroll
        for (int i = 0; i < 2; i++) {
            int g = t + i * 256;                 // 0..511
            int n = g >> 2, kg = g & 3;
            int kgp = kg ^ ((n >> 1) & 3);
            size_t src = (size_t)n * F_IN + k0 + kgp * 8;
            async16(&Bh[g * 8], &Bth[src]);
            async16(&Bl[g * 8], &Btl[src]);
        }
        // A stage: 64x32 fp32 -> split -> swizzled LDS (2 float4/thread)
        #pragma unroll
        for (int i = 0; i < 2; i++) {
            int q = t + i * 256;                 // 0..511
            int r = q >> 3, c4 = q & 7;          // row, float4-chunk (8 per row)
            int grow = row0 + r;
            float4 v = make_float4(0.f, 0.f, 0.f, 0.f);
            if (grow < N_NODES) v = *(const float4*)&x[(size_t)grow * F_IN + k0 + c4 * 4];
            ushort4 uh, ul;
            split2(v.x, uh.x, ul.x); split2(v.y, uh.y, ul.y);
            split2(v.z, uh.z, ul.z); split2(v.w, uh.w, ul.w);
            int gp = (c4 >> 1) ^ ((r >> 1) & 3);
            int idx = r * 32 + gp * 8 + (c4 & 1) * 4;
            *(ushort4*)&Ah[idx] = uh;
            *(ushort4*)&Al[idx] = ul;
        }
        __syncthreads();   // drains DMA + ds_writes

        bf16x8 ah[2], al[2];
        #pragma unroll
        for (int mt = 0; mt < 2; mt++) {
            int arow = wr * 32 + mt * 16 + fr;
            int aidx = arow * 32 + (fkg ^ ((arow >> 1) & 3)) * 8;
            ah[mt] = *(bf16x8*)&Ah[aidx];
            al[mt] = *(bf16x8*)&Al[aidx];
        }
        #pragma unroll
        for (int nt = 0; nt < 4; nt++) {
            int n = wc * 64 + nt * 16 + fr;
            int bidx = n * 32 + (fkg ^ ((n >> 1) & 3)) * 8;
            bf16x8 bh = *(bf16x8*)&Bh[bidx];
            bf16x8 bl = *(bf16x8*)&Bl[bidx];
            #pragma unroll
            for (int mt = 0; mt < 2; mt++) {
                acc[mt][nt] = MFMA16(al[mt], bh, acc[mt][nt]);
                acc[mt][nt] = MFMA16(ah[mt], bl, acc[mt][nt]);
                acc[mt][nt] = MFMA16(ah[mt], bh, acc[mt][nt]);
            }
        }
        __syncthreads();
    }

    const int dcol = lane & 15;
    const int dr0 = (lane >> 4) * 4;
    float dv[2][4];
    #pragma unroll
    for (int mt = 0; mt < 2; mt++)
        #pragma unroll
        for (int j = 0; j < 4; j++) {
            int grow = row0 + wr * 32 + mt * 16 + dr0 + j;
            dv[mt][j] = (grow < N_NODES) ? dinv[grow] : 0.f;
        }
    #pragma unroll
    for (int nt = 0; nt < 4; nt++) {
        int gcol = wc * 64 + nt * 16 + dcol;
        float b = bi[gcol];
        #pragma unroll
        for (int mt = 0; mt < 2; mt++) {
            #pragma unroll
            for (int j = 0; j < 4; j++) {
                int grow = row0 + wr * 32 + mt * 16 + dr0 + j;
                if (grow < N_NODES) {
                    float v = fmaxf(acc[mt][nt][j] + b, 0.f);
                    x0out[(size_t)grow * HID + gcol] = v;
                    g16[(size_t)grow * HID + gcol] = __float2half(dv[mt][j] * v);
                }
            }
        }
    }
}

// ---------------- aggregate: full wave per node, dword lanes, 16 loads in flight ----------------
// comb = 0.8*dd*sum(g16[src]) + (0.8*dd^2+0.1)*h[d] + 0.1*x0[d]
__launch_bounds__(256)
__global__ void aggregate(const int* __restrict__ rowptr, const int* __restrict__ csr,
                          const float* __restrict__ dinv,
                          const __half* __restrict__ g16,
                          const float* __restrict__ h, const float* __restrict__ x0,
                          float* __restrict__ comb) {
    const int node = blockIdx.x * 4 + (threadIdx.x >> 6);
    const int lane = threadIdx.x & 63;
    if (node >= N_NODES) return;

    const unsigned* g32 = (const unsigned*)g16;   // lane owns dword lane = feats 2*lane,2*lane+1
    const float dd = dinv[node];
    const int beg = rowptr[node];                 // wave-uniform -> scalar loads
    const int end = rowptr[node + 1];

    float a0 = 0.f, a1 = 0.f, b0 = 0.f, b1 = 0.f;

    #define GACC(r, i) { \
        __half2 p = *(__half2*)&(r); \
        float2 f = __half22float2(p); \
        if ((i) & 1) { b0 += f.x; b1 += f.y; } else { a0 += f.x; a1 += f.y; } }

    int e = beg;
    for (; e + 16 <= end; e += 16) {
        unsigned r[16];
        #pragma unroll
        for (int i = 0; i < 16; i++) r[i] = g32[(size_t)csr[e + i] * 64 + lane];
        #pragma unroll
        for (int i = 0; i < 16; i++) GACC(r[i], i)
    }
    for (; e + 4 <= end; e += 4) {
        unsigned r[4];
        #pragma unroll
        for (int i = 0; i < 4; i++) r[i] = g32[(size_t)csr[e + i] * 64 + lane];
        #pragma unroll
        for (int i = 0; i < 4; i++) GACC(r[i], i)
    }
    for (; e < end; e++) {
        unsigned r = g32[(size_t)csr[e] * 64 + lane];
        GACC(r, 0)
    }
    #undef GACC

    float s0 = a0 + b0, s1 = a1 + b1;
    const float c1 = 0.8f * dd;
    const float c2 = 0.8f * dd * dd + 0.1f;
    float2 hv = ((const float2*)h)[(size_t)node * 64 + lane];
    float2 xv = ((const float2*)x0)[(size_t)node * 64 + lane];
    float2 o;
    o.x = fmaf(c1, s0, fmaf(c2, hv.x, 0.1f * xv.x));
    o.y = fmaf(c1, s1, fmaf(c2, hv.y, 0.1f * xv.y));
    ((float2*)comb)[(size_t)node * 64 + lane] = o;
}

// ---------------- layer GEMM (MFMA split-bf16, in place): h <- SReLU(comb @ W), g16 ----------------
__launch_bounds__(256)
__global__ void gemm_layer_mfma(const unsigned short* __restrict__ Bth,
                                const unsigned short* __restrict__ Btl,
                                const float* __restrict__ sb,
                                const float* __restrict__ dinv,
                                float* __restrict__ comb,
                                __half* __restrict__ g16, int writeg) {
    __shared__ __align__(16) unsigned short Ah[64 * 128];
    __shared__ __align__(16) unsigned short Al[64 * 128];
    __shared__ __align__(16) unsigned short Bh[128 * 64];
    __shared__ __align__(16) unsigned short Bl[128 * 64];
    const int t = threadIdx.x;
    const int lane = t & 63;
    const int wv = t >> 6;
    const int wr = wv >> 1, wc = wv & 1;
    const int row0 = blockIdx.x * 64;
    const int fr = lane & 15;
    const int fkg = lane >> 4;

    f32x4 acc[2][4] = {};

    auto stageB = [&](int khalf) {
        #pragma unroll
        for (int i = 0; i < 4; i++) {
            int g = t + i * 256;
            int n = g >> 3, j = g & 7;
            int jp = j ^ (n & 7);
            size_t src = (size_t)n * HID + khalf + jp * 8;
            async16(&Bh[g * 8], &Bth[src]);
            async16(&Bl[g * 8], &Btl[src]);
        }
    };

    stageB(0);
    #pragma unroll
    for (int i = 0; i < 8; i++) {
        int q = t + i * 256;
        int r = q >> 5, c4 = q & 31;
        int grow = row0 + r;
        float4 v = make_float4(0.f, 0.f, 0.f, 0.f);
        if (grow < N_NODES) v = *(const float4*)&comb[(size_t)grow * HID + c4 * 4];
        ushort4 uh, ul;
        split2(v.x, uh.x, ul.x); split2(v.y, uh.y, ul.y);
        split2(v.z, uh.z, ul.z); split2(v.w, uh.w, ul.w);
        int idx = (r * 128 + c4 * 4) ^ ((r & 7) << 3);
        *(ushort4*)&Ah[idx] = uh;
        *(ushort4*)&Al[idx] = ul;
    }
    __syncthreads();

    #pragma unroll
    for (int half = 0; half < 2; half++) {
        #pragma unroll
        for (int kk2 = 0; kk2 < 2; kk2++) {
            int kk = half * 2 + kk2;
            bf16x8 ah[2], al[2];
            #pragma unroll
            for (int mt = 0; mt < 2; mt++) {
                int arow = wr * 32 + mt * 16 + fr;
                int aidx = (arow * 128 + kk * 32 + fkg * 8) ^ ((arow & 7) << 3);
                ah[mt] = *(bf16x8*)&Ah[aidx];
                al[mt] = *(bf16x8*)&Al[aidx];
            }
            #pragma unroll
            for (int nt = 0; nt < 4; nt++) {
                int n = wc * 64 + nt * 16 + fr;
                int bidx = (n * 64 + kk2 * 32 + fkg * 8) ^ ((n & 7) << 3);
                bf16x8 bh = *(bf16x8*)&Bh[bidx];
                bf16x8 bl = *(bf16x8*)&Bl[bidx];
                #pragma unroll
                for (int mt = 0; mt < 2; mt++) {
                    acc[mt][nt] = MFMA16(al[mt], bh, acc[mt][nt]);
                    acc[mt][nt] = MFMA16(ah[mt], bl, acc[mt][nt]);
                    acc[mt][nt] = MFMA16(ah[mt], bh, acc[mt][nt]);
                }
            }
        }
        if (half == 0) {
            __syncthreads();
            stageB(64);
            __syncthreads();
        }
    }

    const int dcol = lane & 15;
    const int dr0 = (lane >> 4) * 4;
    float dv[2][4];
    #pragma unroll
    for (int mt = 0; mt < 2; mt++)
        #pragma unroll
        for (int j = 0; j < 4; j++) {
            int grow = row0 + wr * 32 + mt * 16 + dr0 + j;
            dv[mt][j] = (grow < N_NODES) ? dinv[grow] : 0.f;
        }
    #pragma unroll
    for (int nt = 0; nt < 4; nt++) {
        int gcol = wc * 64 + nt * 16 + dcol;
        float s = sb[gcol];
        #pragma unroll
        for (int mt = 0; mt < 2; mt++) {
            #pragma unroll
            for (int j = 0; j < 4; j++) {
                int grow = row0 + wr * 32 + mt * 16 + dr0 + j;
                if (grow < N_NODES) {
                    float v = fmaxf(acc[mt][nt][j], s);
                    comb[(size_t)grow * HID + gcol] = v;
                    if (writeg) g16[(size_t)grow * HID + gcol] = __float2half(dv[mt][j] * v);
                }
            }
        }
    }
}

// ---------------- output GEMM: out = h @ W_out + b_out (fp32 vector) ----------------
__launch_bounds__(256)
__global__ void gemm_out(const float* __restrict__ h, const float* __restrict__ Wo,
                         const float* __restrict__ bo, float* __restrict__ out) {
    __shared__ float As[64][129];
    __shared__ float Ws[128][40];
    const int t = threadIdx.x;
    const int row0 = blockIdx.x * 64;

    #pragma unroll
    for (int i = 0; i < 8; i++) {
        int q = t + i * 256;
        int r = q >> 5, c4 = q & 31;
        int grow = row0 + r;
        float4 v = make_float4(0.f, 0.f, 0.f, 0.f);
        if (grow < N_NODES) v = *(const float4*)&h[(size_t)grow * HID + c4 * 4];
        As[r][c4 * 4 + 0] = v.x;
        As[r][c4 * 4 + 1] = v.y;
        As[r][c4 * 4 + 2] = v.z;
        As[r][c4 * 4 + 3] = v.w;
    }
    #pragma unroll
    for (int i = 0; i < 20; i++) {
        int idx = t + i * 256;
        Ws[idx / 40][idx % 40] = Wo[idx];
    }
    __syncthreads();

    const int r = t >> 2;
    const int c0 = t & 3;
    float acc[10] = {};
    #pragma unroll 4
    for (int k = 0; k < HID; k++) {
        float a = As[r][k];
        #pragma unroll
        for (int i = 0; i < 10; i++) {
            acc[i] = fmaf(a, Ws[k][c0 + 4 * i], acc[i]);
        }
    }
    int grow = row0 + r;
    if (grow < N_NODES) {
        #pragma unroll
        for (int i = 0; i < 10; i++) {
            out[(size_t)grow * C_OUT + c0 + 4 * i] = acc[i] + bo[c0 + 4 * i];
        }
    }
}

// ---------------- launch ----------------
extern "C" void kernel_launch(void* const* d_in, const int* in_sizes, int n_in,
                              void* d_out, int out_size, void* d_ws, size_t ws_size,
                              hipStream_t stream) {
    const float* x   = (const float*)d_in[0];
    const int*   ei  = (const int*)d_in[1];
    const float* Wi  = (const float*)d_in[2];
    const float* bi  = (const float*)d_in[3];
    const float* Wls = (const float*)d_in[4];
    const float* sbs = (const float*)d_in[5];
    const float* Wo  = (const float*)d_in[6];
    const float* bo  = (const float*)d_in[7];
    float* out = (float*)d_out;

    float* dinv    = (float*)d_ws;                  // 50176 f
    int*   indeg   = (int*)(dinv + 50176);          // 50176 i
    int*   rowptr  = indeg + 50176;                 // 50304 i
    int*   cursor  = rowptr + 50304;                // 50176 i
    int*   bsum    = cursor + 50176;                // 256 i
    int*   boff    = bsum + 256;                    // 256 i
    int*   csr     = boff + 256;                    // 800000 i (3.2 MB)
    unsigned short* Wth  = (unsigned short*)(csr + 800000);
    unsigned short* Wtl  = Wth + 65536;
    unsigned short* Wlth = Wtl + 65536;
    unsigned short* Wltl = Wlth + 65536;
    float* x0  = (float*)(Wltl + 65536);            // 6.4M f (residual anchor)
    float* hB  = x0 + (size_t)N_NODES * HID;        // 6.4M f
    float* hC  = hB + (size_t)N_NODES * HID;        // 6.4M f
    __half* g16 = (__half*)(hC + (size_t)N_NODES * HID);  // 6.4M halves (12.8 MB)

    const int edgeBlocks = (E_EDGES + 255) / 256;
    const int gemmBlocks = (N_NODES + 63) / 64;
    const int aggBlocks  = (N_NODES + 3) / 4;       // wave per node, 4 waves/block

    hipMemsetAsync(indeg, 0, N_NODES * sizeof(int), stream);
    indeg_count<<<edgeBlocks, 256, 0, stream>>>(ei, indeg);
    scan_p1<<<SCAN_BLOCKS, 256, 0, stream>>>(indeg, bsum, dinv);
    scan_p2<<<1, 256, 0, stream>>>(bsum, boff, rowptr);
    scan_p3<<<SCAN_BLOCKS, 256, 0, stream>>>(indeg, boff, rowptr, cursor);
    csr_fill<<<edgeBlocks, 256, 0, stream>>>(ei, cursor, csr);
    wprep<<<(2 * F_IN * HID + 255) / 256, 256, 0, stream>>>(Wi, Wls, Wth, Wtl, Wlth, Wltl);

    gemm_in_mfma<<<gemmBlocks, 256, 0, stream>>>(x, Wth, Wtl, bi, dinv, x0, g16);

    float* h = x0;
    for (int l = 0; l < N_LAYERS; l++) {
        float* next = (l & 1) ? hC : hB;
        aggregate<<<aggBlocks, 256, 0, stream>>>(rowptr, csr, dinv, g16, h, x0, next);
        gemm_layer_mfma<<<gemmBlocks, 256, 0, stream>>>(Wlth + (size_t)l * HID * HID,
                                                        Wltl + (size_t)l * HID * HID,
                                                        sbs + (size_t)l * HID, dinv,
                                                        next, g16,
                                                        (l + 1 < N_LAYERS) ? 1 : 0);
        h = next;
    }

    gemm_out<<<gemmBlocks, 256, 0, stream>>>(h, Wo, bo, out);
}